// Round 3
// baseline (669.703 us; speedup 1.0000x reference)
//
#include <hip/hip_runtime.h>
#include <cmath>

// Problem constants: B=32, T=129, D=96, H=64, L=1, SLOPE=0.2
// N = B*(T-1) = 4096
// Outputs (concat in d_out): residuals [N*96], slad [32], hist_jac [N*96*192]

#define TILE_N 64
#define NTHR   512

__global__ void zero_slad_kernel(float* __restrict__ p) {
    if (threadIdx.x < 32) p[threadIdx.x] = 0.0f;
}

__global__ __launch_bounds__(NTHR, 2)
void fused_flow_kernel(const float* __restrict__ x,
                       const float* __restrict__ alphas,
                       const float* __restrict__ W1,
                       const float* __restrict__ b1,
                       const float* __restrict__ W2,
                       const float* __restrict__ b2,
                       float* __restrict__ out_resid,
                       float* __restrict__ out_slad,
                       float* __restrict__ out_hist)
{
    const int i   = blockIdx.y;          // transform index, 0..95
    const int n0  = blockIdx.x * TILE_N; // row-tile base, 0..4032
    const int tid = threadIdx.x;

    // LDS (~125 KB -> 1 block/CU, 8 waves = 2/SIMD)
    __shared__ float sA[13056];   // phase1: sX[d=192][m=68pad]; phase2: sW1T[h=64][d=196pad]
    __shared__ float sW1[12288];  // W1[i] natural [d=192][h=64]
    __shared__ float sG[64*68];   // g^T [h=64][m=68pad]
    __shared__ float sM[96];
    __shared__ float sW2v[64];
    __shared__ float sB1v[64];
    __shared__ float sRes[64*33]; // residual partials [m][th=32], pad 33
    __shared__ float sLog[64];    // per-row log|last| for slad

    // ---- per-i small vectors ----
    if (tid < 96) {
        float v = 0.0f;
        if (tid < i) v = alphas[i*96 + tid];
        else if (tid == i) v = 1.0f;
        sM[tid] = v;
    } else if (tid < 160) {
        sW2v[tid-96] = W2[i*64 + (tid-96)];
    } else if (tid < 224) {
        sB1v[tid-160] = b1[i*64 + (tid-160)];
    }
    __syncthreads();

    // ---- stage W1[i] (48KB, linear, coalesced) ----
    {
        const float4* src = reinterpret_cast<const float4*>(W1 + (size_t)i * 12288);
        float4* dst = reinterpret_cast<float4*>(sW1);
        #pragma unroll
        for (int j = 0; j < 6; ++j) dst[tid + j*NTHR] = src[tid + j*NTHR];
    }

    // ---- stage x tile transposed: sX[d][r], tail half scaled by M[i] ----
    // row n = n0+r: [yy[n] | xx[n]] is a CONTIGUOUS 192-float slice of x.
    {
        const int bb = n0 >> 7;      // batch index (tile never crosses batch: 64 | 128)
        const int t0 = n0 & 127;
        const float* xbase = x + (size_t)(bb*129 + t0) * 96;
        #pragma unroll
        for (int j = 0; j < 6; ++j) {
            int idx = tid + j*NTHR;          // 0..3071
            int r = idx / 48;                // row 0..63
            int c = idx - r*48;              // float4 chunk 0..47
            float4 v = *reinterpret_cast<const float4*>(xbase + r*96 + c*4);
            int d0 = c*4;
            if (d0 >= 96) {
                v.x *= sM[d0-96]; v.y *= sM[d0-95]; v.z *= sM[d0-94]; v.w *= sM[d0-93];
            }
            sA[(d0+0)*68 + r] = v.x;
            sA[(d0+1)*68 + r] = v.y;
            sA[(d0+2)*68 + r] = v.z;
            sA[(d0+3)*68 + r] = v.w;
        }
    }
    __syncthreads();

    // ---- phase 1: h[m=64][hh=64] = sX^T * W1, K = 97+i (masked tail of W1 is zero) ----
    // 512 threads: 16 m-groups (x4) x 32 h-groups (x2)
    const int tm = tid & 15;
    const int th = tid >> 4;      // 0..31
    const int m0 = tm * 4;
    const int h0 = th * 2;

    float acc1[4][2];
    #pragma unroll
    for (int a = 0; a < 4; ++a)
        #pragma unroll
        for (int q = 0; q < 2; ++q) acc1[a][q] = 0.0f;

    const int Kd = 97 + i;
    #pragma unroll 4
    for (int k = 0; k < Kd; ++k) {
        const float4 av = *reinterpret_cast<const float4*>(&sA[k*68 + m0]);
        const float2 bv = *reinterpret_cast<const float2*>(&sW1[(k<<6) + h0]);
        const float am[4] = {av.x, av.y, av.z, av.w};
        const float bh[2] = {bv.x, bv.y};
        #pragma unroll
        for (int a = 0; a < 4; ++a)
            #pragma unroll
            for (int q = 0; q < 2; ++q)
                acc1[a][q] = __builtin_fmaf(am[a], bh[q], acc1[a][q]);
    }

    // ---- epilogue 1: bias, leaky-relu, residual partials, g = dact*W2 (store g^T) ----
    {
        float resp[4] = {0.f, 0.f, 0.f, 0.f};
        #pragma unroll
        for (int q = 0; q < 2; ++q) {
            const float b1q = sB1v[h0+q];
            const float w2q = sW2v[h0+q];
            #pragma unroll
            for (int a = 0; a < 4; ++a) {
                const float hv = acc1[a][q] + b1q;
                const bool pos = hv > 0.0f;
                resp[a] += (pos ? hv : 0.2f*hv) * w2q;
                sG[(h0+q)*68 + (m0+a)] = (pos ? 1.0f : 0.2f) * w2q;
            }
        }
        #pragma unroll
        for (int a = 0; a < 4; ++a) sRes[(m0+a)*33 + th] = resp[a];
    }
    __syncthreads();   // phase1 reads of sA done; sG/sRes complete

    // ---- transpose W1 into sA: sW1T[h][k], rows padded to 196 ----
    #pragma unroll
    for (int j = 0; j < 6; ++j) {
        int idx = tid + j*NTHR;      // 0..3071
        int hh = idx & 63;
        int kc = idx >> 6;           // 0..47
        float4 v;
        v.x = sW1[(kc*4+0)*64 + hh];
        v.y = sW1[(kc*4+1)*64 + hh];
        v.z = sW1[(kc*4+2)*64 + hh];
        v.w = sW1[(kc*4+3)*64 + hh];
        *reinterpret_cast<float4*>(&sA[hh*196 + kc*4]) = v;
    }
    __syncthreads();

    // ---- phase 2: pdd[m=64][d=192] = g * W1^T, K = 64 ----
    // 512 threads: 32 m-groups (x2, tid>>4) x 16 d-groups (x12, tid&15).
    // Columns d > 96+i are structurally zero (masked W1) -> skip their FMA loop.
    const int td  = tid & 15;
    const int tm2 = tid >> 4;      // 0..31
    const int d0  = td * 12;
    const int p0  = tm2 * 2;       // row pair base

    float acc2[2][12];
    #pragma unroll
    for (int a = 0; a < 2; ++a)
        #pragma unroll
        for (int q = 0; q < 12; ++q) acc2[a][q] = 0.0f;

    if (d0 <= 96 + i) {
        #pragma unroll 2
        for (int k = 0; k < 64; ++k) {
            const float2 av  = *reinterpret_cast<const float2*>(&sG[k*68 + p0]);
            const float4 b0v = *reinterpret_cast<const float4*>(&sA[k*196 + d0 + 0]);
            const float4 b1v = *reinterpret_cast<const float4*>(&sA[k*196 + d0 + 4]);
            const float4 b2v = *reinterpret_cast<const float4*>(&sA[k*196 + d0 + 8]);
            const float am[2]  = {av.x, av.y};
            const float bd[12] = {b0v.x, b0v.y, b0v.z, b0v.w,
                                  b1v.x, b1v.y, b1v.z, b1v.w,
                                  b2v.x, b2v.y, b2v.z, b2v.w};
            #pragma unroll
            for (int a = 0; a < 2; ++a)
                #pragma unroll
                for (int q = 0; q < 12; ++q)
                    acc2[a][q] = __builtin_fmaf(am[a], bd[q], acc2[a][q]);
        }
    }

    // ---- extract log|det| column lc=96+i, zero it (compile-time acc indices only) ----
    {
        const int lc  = 96 + i;
        const int tdl = lc / 12;     // owning d-group (uniform per block)
        if (td == tdl) {
            const int qlc = lc - tdl*12;
            #pragma unroll
            for (int q = 0; q < 12; ++q) {
                if (q == qlc) {
                    #pragma unroll
                    for (int a = 0; a < 2; ++a) {
                        sLog[p0+a] = logf(fabsf(acc2[a][q]));
                        acc2[a][q] = 0.0f;
                    }
                }
            }
        }
    }

    // ---- hist_jac direct stores: 16 lanes (td 0..15) cover one 768B row ----
    #pragma unroll
    for (int a = 0; a < 2; ++a) {
        float* row = out_hist + ((size_t)(n0 + p0 + a)*96 + i)*192 + d0;
        *reinterpret_cast<float4*>(row + 0) = make_float4(acc2[a][0], acc2[a][1], acc2[a][2],  acc2[a][3]);
        *reinterpret_cast<float4*>(row + 4) = make_float4(acc2[a][4], acc2[a][5], acc2[a][6],  acc2[a][7]);
        *reinterpret_cast<float4*>(row + 8) = make_float4(acc2[a][8], acc2[a][9], acc2[a][10], acc2[a][11]);
    }
    __syncthreads();   // sLog complete

    // ---- residuals: reduce sRes over th, add b2 ----
    if (tid < 64) {
        float s = b2[i];
        #pragma unroll
        for (int j = 0; j < 32; ++j) s += sRes[tid*33 + j];
        out_resid[(size_t)(n0 + tid)*96 + i] = s;

        // ---- log|det| reduce over 64 rows (wave 0), one atomic per block ----
        float lp = sLog[tid];
        #pragma unroll
        for (int off = 32; off > 0; off >>= 1) lp += __shfl_down(lp, off);
        if (tid == 0) atomicAdd(&out_slad[n0 >> 7], lp);
    }
}

extern "C" void kernel_launch(void* const* d_in, const int* in_sizes, int n_in,
                              void* d_out, int out_size, void* d_ws, size_t ws_size,
                              hipStream_t stream) {
    const float* x      = (const float*)d_in[0];
    const float* alphas = (const float*)d_in[1];
    const float* W1     = (const float*)d_in[2];
    const float* b1     = (const float*)d_in[3];
    const float* W2     = (const float*)d_in[4];
    const float* b2     = (const float*)d_in[5];

    float* out       = (float*)d_out;
    float* out_resid = out;                    // 4096*96
    float* out_slad  = out + 4096*96;          // 32
    float* out_hist  = out + 4096*96 + 32;     // 4096*96*192

    zero_slad_kernel<<<1, 64, 0, stream>>>(out_slad);

    dim3 grid(4096 / TILE_N, 96);   // (64 n-tiles, 96 i)
    fused_flow_kernel<<<grid, NTHR, 0, stream>>>(x, alphas, W1, b1, W2, b2,
                                                 out_resid, out_slad, out_hist);
}

// Round 7
// 651.917 us; speedup vs baseline: 1.0273x; 1.0273x over previous
//
#include <hip/hip_runtime.h>
#include <cmath>

// Problem constants: B=32, T=129, D=96, H=64, L=1, SLOPE=0.2
// N = B*(T-1) = 4096
// Outputs (concat in d_out): residuals [N*96], slad [32], hist_jac [N*96*192]

#define TILE_N 64
#define NTHR   512

__global__ void zero_slad_kernel(float* __restrict__ p) {
    if (threadIdx.x < 32) p[threadIdx.x] = 0.0f;
}

// LDS ~79 KB -> 2 blocks/CU, 16 waves/CU (4/SIMD)
__global__ __launch_bounds__(NTHR, 4)
void fused_flow_kernel(const float* __restrict__ x,
                       const float* __restrict__ alphas,
                       const float* __restrict__ W1,
                       const float* __restrict__ b1,
                       const float* __restrict__ W2,
                       const float* __restrict__ b2,
                       float* __restrict__ out_resid,
                       float* __restrict__ out_slad,
                       float* __restrict__ out_hist)
{
    const int i   = blockIdx.y;          // transform index, 0..95
    const int n0  = blockIdx.x * TILE_N; // row-tile base, 0..4032
    const int tid = threadIdx.x;

    __shared__ float sA[13056];   // phase1: sX[d=192][m=68pad]; phase2: sW1T[h=64][d=196pad]
    __shared__ float sG[64*68];   // g^T [h=64][m=68pad]
    __shared__ float sM[96];
    __shared__ float sW2v[64];
    __shared__ float sB1v[64];
    __shared__ float sRes[64*33]; // residual partials [m][th=32], pad 33
    __shared__ float sLog[64];    // per-row log|last| for slad

    const float* __restrict__ W1i = W1 + (size_t)i * 12288;  // [d=192][h=64], L2-hot (64 blocks share)

    // ---- per-i small vectors ----
    if (tid < 96) {
        float v = 0.0f;
        if (tid < i) v = alphas[i*96 + tid];
        else if (tid == i) v = 1.0f;
        sM[tid] = v;
    } else if (tid < 160) {
        sW2v[tid-96] = W2[i*64 + (tid-96)];
    } else if (tid < 224) {
        sB1v[tid-160] = b1[i*64 + (tid-160)];
    }
    __syncthreads();

    // ---- stage x tile transposed: sX[d][r], tail half scaled by M[i] ----
    // Conflict-free mapping: r = lane (full 32-bank spread on writes), c wave-uniform.
    // Loads are strided-384B but x (1.6MB) is L2/L3-resident.
    {
        const int bb = n0 >> 7;      // batch index (tile never crosses batch: 64 | 128)
        const int t0 = n0 & 127;
        const float* xbase = x + (size_t)(bb*129 + t0) * 96;
        const int r  = tid & 63;
        const int c0 = tid >> 6;     // 0..7, wave-uniform
        #pragma unroll
        for (int j = 0; j < 6; ++j) {
            const int c = c0 + 8*j;          // float4 chunk 0..47
            float4 v = *reinterpret_cast<const float4*>(xbase + r*96 + c*4);
            const int d0 = c*4;
            if (d0 >= 96) {
                v.x *= sM[d0-96]; v.y *= sM[d0-95]; v.z *= sM[d0-94]; v.w *= sM[d0-93];
            }
            sA[(d0+0)*68 + r] = v.x;
            sA[(d0+1)*68 + r] = v.y;
            sA[(d0+2)*68 + r] = v.z;
            sA[(d0+3)*68 + r] = v.w;
        }
    }
    __syncthreads();

    // ---- phase 1: h[m=64][hh=64] = sX^T * W1, K = 97+i (masked tail of W1 is zero) ----
    // 512 threads: 16 m-groups (x4) x 32 h-groups (x2). B-operand streamed from
    // global (lane-broadcast 32B/wave/iter, L2-hot) — no LDS copy of W1.
    const int tm = tid & 15;
    const int th = tid >> 4;      // 0..31
    const int m0 = tm * 4;
    const int h0 = th * 2;

    float acc1[4][2];
    #pragma unroll
    for (int a = 0; a < 4; ++a)
        #pragma unroll
        for (int q = 0; q < 2; ++q) acc1[a][q] = 0.0f;

    const int Kd = 97 + i;
    const float* __restrict__ bptr = W1i + h0;
    #pragma unroll 4
    for (int k = 0; k < Kd; ++k) {
        const float4 av = *reinterpret_cast<const float4*>(&sA[k*68 + m0]);
        const float2 bv = *reinterpret_cast<const float2*>(bptr + (k<<6));
        const float am[4] = {av.x, av.y, av.z, av.w};
        const float bh[2] = {bv.x, bv.y};
        #pragma unroll
        for (int a = 0; a < 4; ++a)
            #pragma unroll
            for (int q = 0; q < 2; ++q)
                acc1[a][q] = __builtin_fmaf(am[a], bh[q], acc1[a][q]);
    }

    // ---- epilogue 1: bias, leaky-relu, residual partials, g = dact*W2 (store g^T) ----
    {
        float resp[4] = {0.f, 0.f, 0.f, 0.f};
        #pragma unroll
        for (int q = 0; q < 2; ++q) {
            const float b1q = sB1v[h0+q];
            const float w2q = sW2v[h0+q];
            #pragma unroll
            for (int a = 0; a < 4; ++a) {
                const float hv = acc1[a][q] + b1q;
                const bool pos = hv > 0.0f;
                resp[a] += (pos ? hv : 0.2f*hv) * w2q;
                sG[(h0+q)*68 + (m0+a)] = (pos ? 1.0f : 0.2f) * w2q;
            }
        }
        #pragma unroll
        for (int a = 0; a < 4; ++a) sRes[(m0+a)*33 + th] = resp[a];
    }
    __syncthreads();   // phase1 reads of sA done; sG/sRes complete

    // ---- stage W1T into sA from GLOBAL: sW1T[h=64][d=196pad] ----
    // Reads: 4 coalesced 256B rows per (kc); writes: b128, dense.
    {
        const int hh  = tid & 63;
        const int kc0 = tid >> 6;    // 0..7, wave-uniform
        #pragma unroll
        for (int j = 0; j < 6; ++j) {
            const int kc = kc0 + 8*j;   // 0..47
            float4 v;
            v.x = W1i[(kc*4+0)*64 + hh];
            v.y = W1i[(kc*4+1)*64 + hh];
            v.z = W1i[(kc*4+2)*64 + hh];
            v.w = W1i[(kc*4+3)*64 + hh];
            *reinterpret_cast<float4*>(&sA[hh*196 + kc*4]) = v;
        }
    }
    __syncthreads();

    // ---- phase 2: pdd[m=64][d=192] = g * W1^T, K = 64 ----
    // 512 threads: 32 m-groups (x2, tid>>4) x 16 d-groups (x12, tid&15).
    // Columns d > 96+i are structurally zero (masked W1) -> skip their FMA loop.
    const int td  = tid & 15;
    const int tm2 = tid >> 4;      // 0..31
    const int d0  = td * 12;
    const int p0  = tm2 * 2;       // row pair base

    float acc2[2][12];
    #pragma unroll
    for (int a = 0; a < 2; ++a)
        #pragma unroll
        for (int q = 0; q < 12; ++q) acc2[a][q] = 0.0f;

    if (d0 <= 96 + i) {
        #pragma unroll 2
        for (int k = 0; k < 64; ++k) {
            const float2 av  = *reinterpret_cast<const float2*>(&sG[k*68 + p0]);
            const float4 b0v = *reinterpret_cast<const float4*>(&sA[k*196 + d0 + 0]);
            const float4 b1v = *reinterpret_cast<const float4*>(&sA[k*196 + d0 + 4]);
            const float4 b2v = *reinterpret_cast<const float4*>(&sA[k*196 + d0 + 8]);
            const float am[2]  = {av.x, av.y};
            const float bd[12] = {b0v.x, b0v.y, b0v.z, b0v.w,
                                  b1v.x, b1v.y, b1v.z, b1v.w,
                                  b2v.x, b2v.y, b2v.z, b2v.w};
            #pragma unroll
            for (int a = 0; a < 2; ++a)
                #pragma unroll
                for (int q = 0; q < 12; ++q)
                    acc2[a][q] = __builtin_fmaf(am[a], bd[q], acc2[a][q]);
        }
    }

    // ---- extract log|det| column lc=96+i, zero it (compile-time acc indices only) ----
    {
        const int lc  = 96 + i;
        const int tdl = lc / 12;     // owning d-group (uniform per block)
        if (td == tdl) {
            const int qlc = lc - tdl*12;
            #pragma unroll
            for (int q = 0; q < 12; ++q) {
                if (q == qlc) {
                    #pragma unroll
                    for (int a = 0; a < 2; ++a) {
                        sLog[p0+a] = logf(fabsf(acc2[a][q]));
                        acc2[a][q] = 0.0f;
                    }
                }
            }
        }
    }

    // ---- hist_jac direct stores: 16 lanes (td 0..15) cover one 768B row ----
    #pragma unroll
    for (int a = 0; a < 2; ++a) {
        float* row = out_hist + ((size_t)(n0 + p0 + a)*96 + i)*192 + d0;
        *reinterpret_cast<float4*>(row + 0) = make_float4(acc2[a][0], acc2[a][1], acc2[a][2],  acc2[a][3]);
        *reinterpret_cast<float4*>(row + 4) = make_float4(acc2[a][4], acc2[a][5], acc2[a][6],  acc2[a][7]);
        *reinterpret_cast<float4*>(row + 8) = make_float4(acc2[a][8], acc2[a][9], acc2[a][10], acc2[a][11]);
    }
    __syncthreads();   // sLog complete

    // ---- residuals: reduce sRes over th, add b2 ----
    if (tid < 64) {
        float s = b2[i];
        #pragma unroll
        for (int j = 0; j < 32; ++j) s += sRes[tid*33 + j];
        out_resid[(size_t)(n0 + tid)*96 + i] = s;

        // ---- log|det| reduce over 64 rows (wave 0), one atomic per block ----
        float lp = sLog[tid];
        #pragma unroll
        for (int off = 32; off > 0; off >>= 1) lp += __shfl_down(lp, off);
        if (tid == 0) atomicAdd(&out_slad[n0 >> 7], lp);
    }
}

extern "C" void kernel_launch(void* const* d_in, const int* in_sizes, int n_in,
                              void* d_out, int out_size, void* d_ws, size_t ws_size,
                              hipStream_t stream) {
    const float* x      = (const float*)d_in[0];
    const float* alphas = (const float*)d_in[1];
    const float* W1     = (const float*)d_in[2];
    const float* b1     = (const float*)d_in[3];
    const float* W2     = (const float*)d_in[4];
    const float* b2     = (const float*)d_in[5];

    float* out       = (float*)d_out;
    float* out_resid = out;                    // 4096*96
    float* out_slad  = out + 4096*96;          // 32
    float* out_hist  = out + 4096*96 + 32;     // 4096*96*192

    zero_slad_kernel<<<1, 64, 0, stream>>>(out_slad);

    dim3 grid(4096 / TILE_N, 96);   // (64 n-tiles, 96 i)
    fused_flow_kernel<<<grid, NTHR, 0, stream>>>(x, alphas, W1, b1, W2, b2,
                                                 out_resid, out_slad, out_hist);
}